// Round 3
// baseline (2233.514 us; speedup 1.0000x reference)
//
#include <hip/hip_runtime.h>
#include <hip/hip_bf16.h>

#define NS 16384   // batch
#define H 256      // hidden
#define TH 768     // 3H
#define PRED 24    // decode steps
#define BM 64      // rows per block
#define LDA 272    // LDS h-tile stride (bf16 elems): 16B-aligned rows, 4-way max banks

typedef short bf16x8 __attribute__((ext_vector_type(8)));
typedef float floatx4 __attribute__((ext_vector_type(4)));

__device__ __forceinline__ float b2f(unsigned short u) {
    return __uint_as_float(((unsigned int)u) << 16);
}
__device__ __forceinline__ unsigned short f2b(float f) {   // RTN-even bf16
    unsigned int u = __float_as_uint(f);
    return (unsigned short)((u + 0x7FFFu + ((u >> 16) & 1u)) >> 16);
}
__device__ __forceinline__ float fsig(float v) {
    return __builtin_amdgcn_rcpf(1.0f + __expf(-v));       // saturates at +/-inf
}
__device__ __forceinline__ float ftanh(float v) {
    return 1.0f - 2.0f * __builtin_amdgcn_rcpf(1.0f + __expf(2.0f * v));
}

// Fully fused 24-step autoregressive GRU decode. 256 blocks x 512 thr.
// Block owns 64 rows end-to-end; NO workspace use; input dtype probed at runtime.
// Wave wid: rh=wid&3 owns rows rh*16..+16; ch=wid>>2 owns hidden cols ch*128..+128.
__global__ __launch_bounds__(512, 2)
void decode_all(const void* __restrict__ encP,   const void* __restrict__ wprojP,
                const void* __restrict__ bprojP, const void* __restrict__ WihP,
                const void* __restrict__ bihP,   const void* __restrict__ WhhP,
                const void* __restrict__ bhhP,   const void* __restrict__ woutP,
                const void* __restrict__ boutP,  void* __restrict__ outP) {
    __shared__ __align__(16) unsigned short As[BM * LDA];   // 34.8 KB bf16 h-tile
    __shared__ float u_lds[TH], c_lds[TH];    // rank-1 gate constants
    __shared__ float bhn_lds[H], wo_lds[H];
    __shared__ float wp_lds[H], bp_lds[H];
    __shared__ float pred_lds[2][BM];
    __shared__ int sflag;

    const int tid  = threadIdx.x;
    const int wid  = tid >> 6;
    const int lane = tid & 63;
    const int lo   = lane & 15;
    const int quad = lane >> 4;
    const int rh   = wid & 3;        // row-group
    const int ch   = wid >> 2;       // col-half
    const int m0   = blockIdx.x * BM;

    // ---- phase 0: probe input dtype ----
    if (tid == 0) sflag = 0;
    __syncthreads();
    {
        float v = b2f(((const unsigned short*)WihP)[tid]);
        if (!(fabsf(v) <= 0.25f)) sflag = 1;   // catches huge values and NaN
    }
    __syncthreads();
    const bool f32in = (sflag != 0);

    const float*          encF = (const float*)encP;
    const unsigned short* encB = (const unsigned short*)encP;
    const float*          WhhF = (const float*)WhhP;
    const unsigned short* WhhB = (const unsigned short*)WhhP;

    // ---- phase 1: small vectors to LDS ----
    if (tid < H) {
        wp_lds[tid] = f32in ? ((const float*)wprojP)[tid] : b2f(((const unsigned short*)wprojP)[tid]);
        bp_lds[tid] = f32in ? ((const float*)bprojP)[tid] : b2f(((const unsigned short*)bprojP)[tid]);
        wo_lds[tid] = f32in ? ((const float*)woutP)[tid]  : b2f(((const unsigned short*)woutP)[tid]);
    }
    __syncthreads();

    // ---- phase 2: rank-1 collapse  u = W_ih@w_proj ; c = W_ih@b_proj + b_ih (+b_hh for r,z) ----
    for (int j = tid; j < TH; j += 512) {
        float su = 0.f, sc = 0.f;
        if (f32in) {
            const float* row = (const float*)WihP + (size_t)j * H;
#pragma unroll 4
            for (int k = 0; k < H; ++k) { float w = row[k]; su = fmaf(w, wp_lds[k], su); sc = fmaf(w, bp_lds[k], sc); }
        } else {
            const unsigned short* row = (const unsigned short*)WihP + (size_t)j * H;
#pragma unroll 4
            for (int k = 0; k < H; ++k) { float w = b2f(row[k]); su = fmaf(w, wp_lds[k], su); sc = fmaf(w, bp_lds[k], sc); }
        }
        float bih = f32in ? ((const float*)bihP)[j] : b2f(((const unsigned short*)bihP)[j]);
        float bhh = f32in ? ((const float*)bhhP)[j] : b2f(((const unsigned short*)bhhP)[j]);
        u_lds[j] = su;
        c_lds[j] = sc + bih + (j < 512 ? bhh : 0.f);   // b_hh folds into r,z only
        if (j >= 512) bhn_lds[j - 512] = bhh;          // n-gate: r*(gh_n + b_hh_n)
    }

    // ---- phase 3: stage h0 tile (bf16) + fp32 hold registers ----
    for (int i = tid; i < BM * H; i += 512) {
        int r = i >> 8, col = i & 255;
        float hv = f32in ? encF[(size_t)(m0 + r) * H + col]
                         : b2f(encB[(size_t)(m0 + r) * H + col]);
        As[r * LDA + col] = f2b(hv);
    }
    float hold[8][4];                         // lane owns (row=rh*16+quad*4+v, col=ch*128+sc*16+lo)
#pragma unroll
    for (int sc = 0; sc < 8; ++sc)
#pragma unroll
        for (int v = 0; v < 4; ++v) {
            int row = m0 + rh * 16 + quad * 4 + v;
            int jj  = ch * 128 + sc * 16 + lo;
            hold[sc][v] = f32in ? encF[(size_t)row * H + jj] : b2f(encB[(size_t)row * H + jj]);
        }
    const float b0 = f32in ? ((const float*)boutP)[0] : b2f(((const unsigned short*)boutP)[0]);

    float xm[4] = {0.f, 0.f, 0.f, 0.f};       // start token x=0
    __syncthreads();

    const int aBase = (rh * 16 + lo) * LDA;   // A-frag: m = lane&15
    const int wCol0 = ch * 128 + lo;          // B rows this wave covers

#pragma unroll 1
    for (int t = 0; t < PRED; ++t) {
        floatx4 acc[3][8];
#pragma unroll
        for (int g = 0; g < 3; ++g)
#pragma unroll
            for (int s = 0; s < 8; ++s) acc[g][s] = (floatx4){0.f, 0.f, 0.f, 0.f};

        // ---- K-loop: gh = h @ W_hh^T (16 rows x 384 gate-cols per wave) ----
        if (f32in) {
#pragma unroll 1
            for (int kk = 0; kk < 8; ++kk) {
                bf16x8 a = *(const bf16x8*)&As[aBase + kk * 32 + quad * 8];
#pragma unroll
                for (int g = 0; g < 3; ++g)
#pragma unroll
                    for (int s = 0; s < 8; ++s) {
                        const float* wr = WhhF + (size_t)(g * 256 + wCol0 + s * 16) * H + kk * 32 + quad * 8;
                        float4 w0 = *(const float4*)wr;
                        float4 w1 = *(const float4*)(wr + 4);
                        bf16x8 b;
                        b[0] = (short)f2b(w0.x); b[1] = (short)f2b(w0.y);
                        b[2] = (short)f2b(w0.z); b[3] = (short)f2b(w0.w);
                        b[4] = (short)f2b(w1.x); b[5] = (short)f2b(w1.y);
                        b[6] = (short)f2b(w1.z); b[7] = (short)f2b(w1.w);
                        acc[g][s] = __builtin_amdgcn_mfma_f32_16x16x32_bf16(a, b, acc[g][s], 0, 0, 0);
                    }
            }
        } else {
#pragma unroll 1
            for (int kk = 0; kk < 8; ++kk) {
                bf16x8 a = *(const bf16x8*)&As[aBase + kk * 32 + quad * 8];
#pragma unroll
                for (int g = 0; g < 3; ++g)
#pragma unroll
                    for (int s = 0; s < 8; ++s) {
                        bf16x8 b = *(const bf16x8*)(WhhB + (size_t)(g * 256 + wCol0 + s * 16) * H + kk * 32 + quad * 8);
                        acc[g][s] = __builtin_amdgcn_mfma_f32_16x16x32_bf16(a, b, acc[g][s], 0, 0, 0);
                    }
            }
        }
        __syncthreads();   // all waves done reading As(t)

        // ---- epilogue: gates + h update + pred partials ----
        float p[4] = {0.f, 0.f, 0.f, 0.f};
#pragma unroll
        for (int s = 0; s < 8; ++s) {
            const int jj = ch * 128 + s * 16 + lo;
            const float ur = u_lds[jj], uz = u_lds[256 + jj], un = u_lds[512 + jj];
            const float cr = c_lds[jj], cz = c_lds[256 + jj], cn = c_lds[512 + jj];
            const float bhn = bhn_lds[jj], wo = wo_lds[jj];
#pragma unroll
            for (int v = 0; v < 4; ++v) {
                const float xv = xm[v];
                float r  = fsig(fmaf(xv, ur, cr) + acc[0][s][v]);
                float z  = fsig(fmaf(xv, uz, cz) + acc[1][s][v]);
                float n  = ftanh(fmaf(xv, un, cn) + r * (acc[2][s][v] + bhn));
                float hn = fmaf(z, hold[s][v] - n, n);   // (1-z)*n + z*h
                hold[s][v] = hn;
                As[(rh * 16 + quad * 4 + v) * LDA + jj] = f2b(hn);
                p[v] = fmaf(hn, wo, p[v]);
            }
        }
#pragma unroll
        for (int v = 0; v < 4; ++v) {
            float pv = p[v];
            pv += __shfl_xor(pv, 1, 64);
            pv += __shfl_xor(pv, 2, 64);
            pv += __shfl_xor(pv, 4, 64);
            pv += __shfl_xor(pv, 8, 64);
            if (lo == 0) pred_lds[ch][rh * 16 + quad * 4 + v] = pv;
        }
        __syncthreads();   // As(t+1) + pred partials visible

        // ---- finalize: pred -> x feedback + output column t ----
#pragma unroll
        for (int v = 0; v < 4; ++v) {
            const int ml = rh * 16 + quad * 4 + v;
            xm[v] = b0 + pred_lds[0][ml] + pred_lds[1][ml];
        }
        if (tid < BM) {
            float pr = b0 + pred_lds[0][tid] + pred_lds[1][tid];
            if (f32in) ((float*)outP)[(size_t)(m0 + tid) * PRED + t] = pr;
            else ((unsigned short*)outP)[(size_t)(m0 + tid) * PRED + t] = f2b(pr);
        }
    }
}

extern "C" void kernel_launch(void* const* d_in, const int* in_sizes, int n_in,
                              void* d_out, int out_size, void* d_ws, size_t ws_size,
                              hipStream_t stream) {
    // d_ws deliberately UNUSED (ws_size unknown -> zero-workspace design)
    decode_all<<<NS / BM, 512, 0, stream>>>(d_in[0], d_in[1], d_in[2], d_in[3],
                                            d_in[4], d_in[5], d_in[6], d_in[7],
                                            d_in[8], d_out);
}

// Round 4
// 472.516 us; speedup vs baseline: 4.7269x; 4.7269x over previous
//
#include <hip/hip_runtime.h>
#include <hip/hip_bf16.h>

#define NS 16384   // batch
#define H 256      // hidden
#define TH 768     // 3H
#define PRED 24    // decode steps
#define LDA 272    // LDS h-tile row stride (shorts); R3-verified
#define WS_NEEDED (425984)

typedef short bf16x8 __attribute__((ext_vector_type(8)));
typedef float floatx4 __attribute__((ext_vector_type(4)));

__device__ __forceinline__ float b2f(unsigned short u) {
    return __uint_as_float(((unsigned int)u) << 16);
}
__device__ __forceinline__ unsigned short f2b(float f) {   // RTN-even bf16
    unsigned int u = __float_as_uint(f);
    return (unsigned short)((u + 0x7FFFu + ((u >> 16) & 1u)) >> 16);
}
__device__ __forceinline__ float fsig(float v) {
    return __builtin_amdgcn_rcpf(1.0f + __expf(-v));
}
__device__ __forceinline__ float ftanh(float v) {
    return 1.0f - 2.0f * __builtin_amdgcn_rcpf(1.0f + __expf(2.0f * v));
}

// ================= prep 1: rank-1 input-proj collapse + small vectors =================
// u = W_ih@w_proj ; c = W_ih@b_proj + b_ih (+ b_hh folded for r,z); bhn = b_hh[n-part]
__global__ void prep_proj(const void* __restrict__ WihP, const void* __restrict__ wprojP,
                          const void* __restrict__ bprojP, const void* __restrict__ bihP,
                          const void* __restrict__ bhhP, const void* __restrict__ woutP,
                          const void* __restrict__ boutP,
                          float* __restrict__ u, float* __restrict__ c,
                          float* __restrict__ bhn, float* __restrict__ wo,
                          float* __restrict__ b0) {
    const int j = blockIdx.x;        // 768
    const int lane = threadIdx.x;    // 64
    // dtype probe: bf16 inputs (|W_ih| <= 1/16) vs f32 (random high halfwords)
    unsigned long long bm = __ballot(!(fabsf(b2f(((const unsigned short*)WihP)[lane])) <= 0.25f));
    const bool f32in = (bm != 0ull);

    float su = 0.f, sc = 0.f;
    if (f32in) {
        const float* row = (const float*)WihP + (size_t)j * H;
        const float* wp = (const float*)wprojP;
        const float* bp = (const float*)bprojP;
        for (int k = lane; k < H; k += 64) {
            float w = row[k];
            su = fmaf(w, wp[k], su); sc = fmaf(w, bp[k], sc);
        }
    } else {
        const unsigned short* row = (const unsigned short*)WihP + (size_t)j * H;
        const unsigned short* wp = (const unsigned short*)wprojP;
        const unsigned short* bp = (const unsigned short*)bprojP;
        for (int k = lane; k < H; k += 64) {
            float w = b2f(row[k]);
            su = fmaf(w, b2f(wp[k]), su); sc = fmaf(w, b2f(bp[k]), sc);
        }
    }
    for (int m = 32; m; m >>= 1) { su += __shfl_xor(su, m, 64); sc += __shfl_xor(sc, m, 64); }

    if (lane == 0) {
        float bih = f32in ? ((const float*)bihP)[j] : b2f(((const unsigned short*)bihP)[j]);
        float bhh = f32in ? ((const float*)bhhP)[j] : b2f(((const unsigned short*)bhhP)[j]);
        u[j] = su;
        c[j] = sc + bih + (j < 512 ? bhh : 0.f);
        if (j >= 512) bhn[j - 512] = bhh;
    }
    if (j < H && lane == 1)
        wo[j] = f32in ? ((const float*)woutP)[j] : b2f(((const unsigned short*)woutP)[j]);
    if (j == 0 && lane == 2)
        b0[0] = f32in ? ((const float*)boutP)[0] : b2f(((const unsigned short*)boutP)[0]);
}

// ================= prep 2: swizzle W_hh into MFMA-fragment-contiguous bf16 =================
// Wp chunk layout: frag fi = (w*8 + kk)*3 + g ; within frag: lane*8 elems.
// Wp[fi*512 + lane*8 + e] = W_hh[(g*256 + w*16 + (lane&15))*256 + kk*32 + (lane>>4)*8 + e]
__global__ void prep_swz(const void* __restrict__ WhhP, unsigned short* __restrict__ Wp) {
    const int cidx = blockIdx.x * 256 + threadIdx.x;   // 24576 chunks of 8 elems
    unsigned long long bm = __ballot(!(fabsf(b2f(((const unsigned short*)WhhP)[threadIdx.x & 63])) <= 0.25f));
    const bool f32in = (bm != 0ull);

    const int lane = cidx & 63;
    const int fi   = cidx >> 6;
    const int g    = fi % 3;
    const int kk   = (fi / 3) & 7;
    const int w    = fi / 24;
    const size_t src = (size_t)(g * 256 + w * 16 + (lane & 15)) * H + kk * 32 + (lane >> 4) * 8;
    unsigned short* dst = Wp + (size_t)cidx * 8;
    if (f32in) {
        const float* s = (const float*)WhhP + src;
#pragma unroll
        for (int e = 0; e < 8; ++e) dst[e] = f2b(s[e]);
    } else {
        const unsigned short* s = (const unsigned short*)WhhP + src;
#pragma unroll
        for (int e = 0; e < 8; ++e) dst[e] = s[e];
    }
}

// ================= fused 24-step decode, swizzled-W path =================
// 256 blocks x 1024 thr (16 waves, 4/SIMD). Block owns 64 rows; wave w owns
// h-cols [16w,16w+16) => gate triple (r,z,n) is wave-local; acc = 12 tiles (48 f32).
// W streams from ws as contiguous 1KB frags (coalesced, channel-spread).
__global__ __launch_bounds__(1024)
void decode_swz(const void* __restrict__ encP, const void* __restrict__ WihP,
                const unsigned short* __restrict__ Wp,
                const float* __restrict__ u, const float* __restrict__ c,
                const float* __restrict__ bhnA, const float* __restrict__ woA,
                const float* __restrict__ b0A, void* __restrict__ outP) {
    __shared__ __align__(16) unsigned short As[64 * LDA];   // 34.8 KB bf16 h tile
    __shared__ float pred_part[16][64];
    __shared__ float pred_fin[64];
    __shared__ int sflag;

    const int tid  = threadIdx.x;
    const int w    = tid >> 6;
    const int lane = tid & 63;
    const int lo   = lane & 15;
    const int quad = lane >> 4;
    const int m0   = blockIdx.x * 64;

    // dtype probe (enc/out only; W already handled by prep)
    if (tid == 0) sflag = 0;
    __syncthreads();
    if (!(fabsf(b2f(((const unsigned short*)WihP)[tid])) <= 0.25f)) sflag = 1;
    __syncthreads();
    const bool f32in = (sflag != 0);

    const float*          encF = (const float*)encP;
    const unsigned short* encB = (const unsigned short*)encP;

    // stage h0 tile (bf16)
    for (int i = tid; i < 64 * H; i += 1024) {
        int r = i >> 8, col = i & 255;
        float hv = f32in ? encF[(size_t)(m0 + r) * H + col] : b2f(encB[(size_t)(m0 + r) * H + col]);
        As[r * LDA + col] = f2b(hv);
    }
    if (tid < 64) pred_fin[tid] = 0.f;   // start token x=0

    // per-lane constants (col jj fixed for whole decode)
    const int jj = w * 16 + lo;
    const float ur = u[jj], uz = u[256 + jj], un = u[512 + jj];
    const float cr = c[jj], cz = c[256 + jj], cn = c[512 + jj];
    const float bh = bhnA[jj], wov = woA[jj];
    const float b0 = b0A[0];

    // fp32 h carried in registers: rows im*16+quad*4+v, col jj
    float hold[4][4];
#pragma unroll
    for (int im = 0; im < 4; ++im)
#pragma unroll
        for (int v = 0; v < 4; ++v) {
            int row = m0 + im * 16 + quad * 4 + v;
            hold[im][v] = f32in ? encF[(size_t)row * H + jj] : b2f(encB[(size_t)row * H + jj]);
        }

    const unsigned short* wpBase = Wp + (size_t)w * 12288 + lane * 8;
    __syncthreads();

#pragma unroll 1
    for (int t = 0; t < PRED; ++t) {
        floatx4 acc[3][4];
#pragma unroll
        for (int g = 0; g < 3; ++g)
#pragma unroll
            for (int im = 0; im < 4; ++im) acc[g][im] = (floatx4){0.f, 0.f, 0.f, 0.f};

        // K-loop: 24 coalesced 1KB W-frag loads + 32 LDS A-frag reads + 96 MFMA
#pragma unroll
        for (int kk = 0; kk < 8; ++kk) {
            bf16x8 b[3];
#pragma unroll
            for (int g = 0; g < 3; ++g)
                b[g] = *(const bf16x8*)(wpBase + (size_t)(kk * 3 + g) * 512);
            bf16x8 a[4];
#pragma unroll
            for (int im = 0; im < 4; ++im)
                a[im] = *(const bf16x8*)&As[(im * 16 + lo) * LDA + kk * 32 + quad * 8];
#pragma unroll
            for (int g = 0; g < 3; ++g)
#pragma unroll
                for (int im = 0; im < 4; ++im)
                    acc[g][im] = __builtin_amdgcn_mfma_f32_16x16x32_bf16(a[im], b[g], acc[g][im], 0, 0, 0);
        }
        __syncthreads();   // all waves done reading As(t)

        // epilogue: gates + h update + pred partials
#pragma unroll
        for (int im = 0; im < 4; ++im) {
#pragma unroll
            for (int v = 0; v < 4; ++v) {
                const int row = im * 16 + quad * 4 + v;
                const float xv = pred_fin[row];
                float r  = fsig(fmaf(xv, ur, cr) + acc[0][im][v]);
                float z  = fsig(fmaf(xv, uz, cz) + acc[1][im][v]);
                float n  = ftanh(fmaf(xv, un, cn) + r * (acc[2][im][v] + bh));
                float hn = fmaf(z, hold[im][v] - n, n);   // (1-z)*n + z*h
                hold[im][v] = hn;
                As[row * LDA + jj] = f2b(hn);
                float pv = hn * wov;
                pv += __shfl_xor(pv, 1, 64);
                pv += __shfl_xor(pv, 2, 64);
                pv += __shfl_xor(pv, 4, 64);
                pv += __shfl_xor(pv, 8, 64);
                if (lo == 0) pred_part[w][row] = pv;
            }
        }
        __syncthreads();   // As(t+1) + partials visible

        // finalize: pred -> feedback + output column t
        if (tid < 64) {
            float pr = b0;
#pragma unroll
            for (int ww = 0; ww < 16; ++ww) pr += pred_part[ww][tid];
            pred_fin[tid] = pr;
            if (f32in) ((float*)outP)[(size_t)(m0 + tid) * PRED + t] = pr;
            else ((unsigned short*)outP)[(size_t)(m0 + tid) * PRED + t] = f2b(pr);
        }
    }
}

// ================= fallback (R3, proven): zero-workspace fused decode =================
__global__ __launch_bounds__(512, 2)
void decode_all(const void* __restrict__ encP,   const void* __restrict__ wprojP,
                const void* __restrict__ bprojP, const void* __restrict__ WihP,
                const void* __restrict__ bihP,   const void* __restrict__ WhhP,
                const void* __restrict__ bhhP,   const void* __restrict__ woutP,
                const void* __restrict__ boutP,  void* __restrict__ outP) {
    __shared__ __align__(16) unsigned short As[64 * LDA];
    __shared__ float u_lds[TH], c_lds[TH];
    __shared__ float bhn_lds[H], wo_lds[H];
    __shared__ float wp_lds[H], bp_lds[H];
    __shared__ float pred_lds[2][64];
    __shared__ int sflag;

    const int tid  = threadIdx.x;
    const int wid  = tid >> 6;
    const int lane = tid & 63;
    const int lo   = lane & 15;
    const int quad = lane >> 4;
    const int rh   = wid & 3;
    const int ch   = wid >> 2;
    const int m0   = blockIdx.x * 64;

    if (tid == 0) sflag = 0;
    __syncthreads();
    if (!(fabsf(b2f(((const unsigned short*)WihP)[tid])) <= 0.25f)) sflag = 1;
    __syncthreads();
    const bool f32in = (sflag != 0);

    const float*          encF = (const float*)encP;
    const unsigned short* encB = (const unsigned short*)encP;
    const unsigned short* WhhB = (const unsigned short*)WhhP;
    const float*          WhhF = (const float*)WhhP;

    if (tid < H) {
        wp_lds[tid] = f32in ? ((const float*)wprojP)[tid] : b2f(((const unsigned short*)wprojP)[tid]);
        bp_lds[tid] = f32in ? ((const float*)bprojP)[tid] : b2f(((const unsigned short*)bprojP)[tid]);
        wo_lds[tid] = f32in ? ((const float*)woutP)[tid]  : b2f(((const unsigned short*)woutP)[tid]);
    }
    __syncthreads();

    for (int j = tid; j < TH; j += 512) {
        float su = 0.f, sc = 0.f;
        if (f32in) {
            const float* row = (const float*)WihP + (size_t)j * H;
            for (int k = 0; k < H; ++k) { float w = row[k]; su = fmaf(w, wp_lds[k], su); sc = fmaf(w, bp_lds[k], sc); }
        } else {
            const unsigned short* row = (const unsigned short*)WihP + (size_t)j * H;
            for (int k = 0; k < H; ++k) { float w = b2f(row[k]); su = fmaf(w, wp_lds[k], su); sc = fmaf(w, bp_lds[k], sc); }
        }
        float bih = f32in ? ((const float*)bihP)[j] : b2f(((const unsigned short*)bihP)[j]);
        float bhh = f32in ? ((const float*)bhhP)[j] : b2f(((const unsigned short*)bhhP)[j]);
        u_lds[j] = su;
        c_lds[j] = sc + bih + (j < 512 ? bhh : 0.f);
        if (j >= 512) bhn_lds[j - 512] = bhh;
    }

    for (int i = tid; i < 64 * H; i += 512) {
        int r = i >> 8, col = i & 255;
        float hv = f32in ? encF[(size_t)(m0 + r) * H + col] : b2f(encB[(size_t)(m0 + r) * H + col]);
        As[r * LDA + col] = f2b(hv);
    }
    float hold[8][4];
#pragma unroll
    for (int s = 0; s < 8; ++s)
#pragma unroll
        for (int v = 0; v < 4; ++v) {
            int row = m0 + rh * 16 + quad * 4 + v;
            int jj  = ch * 128 + s * 16 + lo;
            hold[s][v] = f32in ? encF[(size_t)row * H + jj] : b2f(encB[(size_t)row * H + jj]);
        }
    const float b0 = f32in ? ((const float*)boutP)[0] : b2f(((const unsigned short*)boutP)[0]);

    float xm[4] = {0.f, 0.f, 0.f, 0.f};
    __syncthreads();

    const int aBase = (rh * 16 + lo) * LDA;
    const int wCol0 = ch * 128 + lo;

#pragma unroll 1
    for (int t = 0; t < PRED; ++t) {
        floatx4 acc[3][8];
#pragma unroll
        for (int g = 0; g < 3; ++g)
#pragma unroll
            for (int s = 0; s < 8; ++s) acc[g][s] = (floatx4){0.f, 0.f, 0.f, 0.f};

        if (f32in) {
#pragma unroll 1
            for (int kk = 0; kk < 8; ++kk) {
                bf16x8 a = *(const bf16x8*)&As[aBase + kk * 32 + quad * 8];
#pragma unroll
                for (int g = 0; g < 3; ++g)
#pragma unroll
                    for (int s = 0; s < 8; ++s) {
                        const float* wr = WhhF + (size_t)(g * 256 + wCol0 + s * 16) * H + kk * 32 + quad * 8;
                        float4 w0 = *(const float4*)wr;
                        float4 w1 = *(const float4*)(wr + 4);
                        bf16x8 b;
                        b[0] = (short)f2b(w0.x); b[1] = (short)f2b(w0.y);
                        b[2] = (short)f2b(w0.z); b[3] = (short)f2b(w0.w);
                        b[4] = (short)f2b(w1.x); b[5] = (short)f2b(w1.y);
                        b[6] = (short)f2b(w1.z); b[7] = (short)f2b(w1.w);
                        acc[g][s] = __builtin_amdgcn_mfma_f32_16x16x32_bf16(a, b, acc[g][s], 0, 0, 0);
                    }
            }
        } else {
#pragma unroll 1
            for (int kk = 0; kk < 8; ++kk) {
                bf16x8 a = *(const bf16x8*)&As[aBase + kk * 32 + quad * 8];
#pragma unroll
                for (int g = 0; g < 3; ++g)
#pragma unroll
                    for (int s = 0; s < 8; ++s) {
                        bf16x8 b = *(const bf16x8*)(WhhB + (size_t)(g * 256 + wCol0 + s * 16) * H + kk * 32 + quad * 8);
                        acc[g][s] = __builtin_amdgcn_mfma_f32_16x16x32_bf16(a, b, acc[g][s], 0, 0, 0);
                    }
            }
        }
        __syncthreads();

        float p[4] = {0.f, 0.f, 0.f, 0.f};
#pragma unroll
        for (int s = 0; s < 8; ++s) {
            const int jj = ch * 128 + s * 16 + lo;
            const float urr = u_lds[jj], uzz = u_lds[256 + jj], unn = u_lds[512 + jj];
            const float crr = c_lds[jj], czz = c_lds[256 + jj], cnn = c_lds[512 + jj];
            const float bhn = bhn_lds[jj], wov = wo_lds[jj];
#pragma unroll
            for (int v = 0; v < 4; ++v) {
                const float xv = xm[v];
                float r  = fsig(fmaf(xv, urr, crr) + acc[0][s][v]);
                float z  = fsig(fmaf(xv, uzz, czz) + acc[1][s][v]);
                float n  = ftanh(fmaf(xv, unn, cnn) + r * (acc[2][s][v] + bhn));
                float hn = fmaf(z, hold[s][v] - n, n);
                hold[s][v] = hn;
                As[(rh * 16 + quad * 4 + v) * LDA + jj] = f2b(hn);
                p[v] = fmaf(hn, wov, p[v]);
            }
        }
#pragma unroll
        for (int v = 0; v < 4; ++v) {
            float pv = p[v];
            pv += __shfl_xor(pv, 1, 64);
            pv += __shfl_xor(pv, 2, 64);
            pv += __shfl_xor(pv, 4, 64);
            pv += __shfl_xor(pv, 8, 64);
            if (lo == 0) pred_lds[ch][rh * 16 + quad * 4 + v] = pv;
        }
        __syncthreads();

#pragma unroll
        for (int v = 0; v < 4; ++v) {
            const int ml = rh * 16 + quad * 4 + v;
            xm[v] = b0 + pred_lds[0][ml] + pred_lds[1][ml];
        }
        if (tid < 64) {
            float pr = b0 + pred_lds[0][tid] + pred_lds[1][tid];
            if (f32in) ((float*)outP)[(size_t)(m0 + tid) * PRED + t] = pr;
            else ((unsigned short*)outP)[(size_t)(m0 + tid) * PRED + t] = f2b(pr);
        }
    }
}

extern "C" void kernel_launch(void* const* d_in, const int* in_sizes, int n_in,
                              void* d_out, int out_size, void* d_ws, size_t ws_size,
                              hipStream_t stream) {
    if (ws_size >= (size_t)WS_NEEDED) {
        char* ws = (char*)d_ws;
        unsigned short* Wp = (unsigned short*)ws;          // 393216 B
        float* u   = (float*)(ws + 393216);                // 3072 B
        float* c   = (float*)(ws + 396288);                // 3072 B
        float* bhn = (float*)(ws + 399360);                // 1024 B
        float* wo  = (float*)(ws + 400384);                // 1024 B
        float* b0  = (float*)(ws + 401408);                // 4 B
        prep_proj<<<TH, 64, 0, stream>>>(d_in[3], d_in[1], d_in[2], d_in[4], d_in[6],
                                         d_in[7], d_in[8], u, c, bhn, wo, b0);
        prep_swz<<<96, 256, 0, stream>>>(d_in[5], Wp);
        decode_swz<<<NS / 64, 1024, 0, stream>>>(d_in[0], d_in[3], Wp, u, c, bhn, wo, b0, d_out);
    } else {
        decode_all<<<NS / 64, 512, 0, stream>>>(d_in[0], d_in[1], d_in[2], d_in[3],
                                                d_in[4], d_in[5], d_in[6], d_in[7],
                                                d_in[8], d_out);
    }
}